// Round 2
// baseline (427.577 us; speedup 1.0000x reference)
//
#include <hip/hip_runtime.h>
#include <hip/hip_bf16.h>

#define N_PTS (4096 * 192)
#define NT 4            // point-tiles (of 16) per wave -> 64 points/wave

typedef __bf16 bf16x8 __attribute__((ext_vector_type(8)));
typedef float  f32x4  __attribute__((ext_vector_type(4)));
typedef float  f32x2  __attribute__((ext_vector_type(2)));

// ws layout (bf16 element offsets). Main tiles are [m][k'] with k rows permuted
// by kinv (so MFMA C-layout of layer l == B-frag layout of layer l+1) AND
// column-chunk XOR-swizzled (chunk' = chunk ^ (m&15)) so that a LINEAR
// global_load_lds copy produces a bank-conflict-free LDS image for
// ds_read_b128 at 256B row stride (read applies the same XOR, == l16).
#define W1P 0          // 128x128
#define W2P 16384      // 128x128 (rows 0..127 of w2)
#define W3P 32768      // 128x128
#define WFP 49152      // 128x128
#define WRP 65536      // 64x128
#define W0E 73728      // 128x16  fixup vs posb (global-read, unswizzled)
#define W2E 75776      // 128x16
#define WRE 77824      // 64x16
#define WDE 78848      // 2x128   row0 = wd_hi[kinv], row1 = wd_lo[kinv]
#define WOE 79104      // 8x64    rows0-2 = wo_hi ch, rows4-6 = wo_lo ch
// total span = 79616 bf16 = 159,232 B

__device__ __forceinline__ int kinv(int k) {
  int c = k >> 5, q = (k >> 3) & 3, h = (k >> 2) & 1, r = k & 3;
  return (2 * c + h) * 16 + q * 4 + r;
}

__global__ void prep_kernel(const float* __restrict__ w0, const float* __restrict__ w1,
                            const float* __restrict__ w2, const float* __restrict__ w3,
                            const float* __restrict__ wf, const float* __restrict__ wr,
                            const float* __restrict__ wd, const float* __restrict__ wo,
                            __bf16* __restrict__ ws) {
  int i = blockIdx.x * 256 + threadIdx.x;
  if (i < 65536) {                       // w1,w2,w3,wf main tiles: k-permuted + swizzled
    int t = i >> 14, j = i & 16383, m = j >> 7, col = j & 127;
    int k = (((col >> 3) ^ (m & 15)) << 3) | (col & 7);
    int p = kinv(k);
    const float* w = (t == 0) ? w1 : (t == 1) ? w2 : (t == 2) ? w3 : wf;
    ws[i] = (__bf16)w[p * 128 + m];
  } else if (i < 73728) {                // wr main tile
    int j = i - 65536, m = j >> 7, col = j & 127;
    int k = (((col >> 3) ^ (m & 15)) << 3) | (col & 7);
    int p = kinv(k);
    ws[i] = (__bf16)wr[p * 64 + m];
  } else if (i < 75776) {                // W0E (k-space = posb, no permutation)
    int j = i - 73728, f = j >> 4, k = j & 15; float v = 0.f;
    if (k < 3)      v = w0[k * 128 + f];
    else if (k < 6) v = w0[(k - 3) * 128 + f];
    else if (k < 9) { float w = w0[(k - 6) * 128 + f]; v = w - (float)(__bf16)w; }
    ws[i] = (__bf16)v;
  } else if (i < 77824) {                // W2E
    int j = i - 75776, f = j >> 4, k = j & 15; float v = 0.f;
    if (k < 3)      v = w2[(128 + k) * 128 + f];
    else if (k < 6) v = w2[(128 + k - 3) * 128 + f];
    else if (k < 9) { float w = w2[(128 + k - 6) * 128 + f]; v = w - (float)(__bf16)w; }
    ws[i] = (__bf16)v;
  } else if (i < 78848) {                // WRE
    int j = i - 77824, n = j >> 4, k = j & 15; float v = 0.f;
    if (k >= 9 && k < 15) v = wr[(128 + ((k - 9) % 3)) * 64 + n];
    ws[i] = (__bf16)v;
  } else if (i < 79104) {                // WDE: wd hi/lo, k-permuted
    int j = i - 78848, row = j >> 7, k = j & 127, p = kinv(k);
    float v = wd[p];
    ws[i] = (row == 0) ? (__bf16)v : (__bf16)(v - (float)(__bf16)v);
  } else if (i < 79616) {                // WOE: wo hi/lo, k64-permuted
    int j = i - 79104, row = j >> 6, k = j & 63, p = kinv(k);
    float v = 0.f;
    if (row < 3)                 v = wo[p * 3 + row];
    else if (row >= 4 && row < 7) { float w = wo[p * 3 + row - 4]; v = w - (float)(__bf16)w; }
    ws[i] = (__bf16)v;
  }
}

__device__ __forceinline__ bf16x8 zero8() {
  bf16x8 z;
#pragma unroll
  for (int i = 0; i < 8; ++i) z[i] = (__bf16)0.f;
  return z;
}

__device__ __forceinline__ bf16x8 pack_relu(f32x4 e, f32x4 o) {
  bf16x8 v;
#pragma unroll
  for (int r = 0; r < 4; ++r) {
    v[r]     = (__bf16)fmaxf(e[r], 0.f);
    v[4 + r] = (__bf16)fmaxf(o[r], 0.f);
  }
  return v;
}

// Cooperative global->LDS stage of NB bytes (512 threads, 16B/lane/round).
template <int NB>
__device__ __forceinline__ void stage_tile(const __bf16* __restrict__ gsrc,
                                           __bf16* lds, int wv, int lane) {
  const char* g = (const char*)gsrc;
  char* l = (char*)lds;
#pragma unroll
  for (int r = 0; r < NB; r += 8192) {
    const char* src = g + r + wv * 1024 + lane * 16;
    char* dst = l + r + wv * 1024;                        // wave-uniform base
    __builtin_amdgcn_global_load_lds(
        (const __attribute__((address_space(1))) void*)src,
        (__attribute__((address_space(3))) void*)dst, 16, 0, 0);
  }
}

// One layer from LDS-resident swizzled weights. K=128, acts in registers.
template <int NPAIR, bool FIX>
__device__ __forceinline__ void mlayer(const __bf16* __restrict__ wlds,
                                       const float* __restrict__ bias,
                                       const __bf16* __restrict__ wext,
                                       const bf16x8 (&pf)[NT],
                                       const bf16x8 (&hin)[4][NT],
                                       bf16x8 (&hout)[NPAIR][NT],
                                       int l16, int quad) {
#pragma unroll
  for (int pr = 0; pr < NPAIR; ++pr) {
    f32x4 acc0[NT], acc1[NT];
    f32x4 bv0 = *(const f32x4*)(bias + pr * 32 + quad * 4);
    f32x4 bv1 = *(const f32x4*)(bias + pr * 32 + 16 + quad * 4);
#pragma unroll
    for (int nt = 0; nt < NT; ++nt) { acc0[nt] = bv0; acc1[nt] = bv1; }
#pragma unroll
    for (int c = 0; c < 4; ++c) {
      int chunk = ((c * 4 + quad) ^ l16) << 3;           // swizzled column chunk
      bf16x8 a0 = *(const bf16x8*)(wlds + (pr * 32 + l16) * 128 + chunk);
      bf16x8 a1 = *(const bf16x8*)(wlds + (pr * 32 + 16 + l16) * 128 + chunk);
#pragma unroll
      for (int nt = 0; nt < NT; ++nt) {
        acc0[nt] = __builtin_amdgcn_mfma_f32_16x16x32_bf16(a0, hin[c][nt], acc0[nt], 0, 0, 0);
        acc1[nt] = __builtin_amdgcn_mfma_f32_16x16x32_bf16(a1, hin[c][nt], acc1[nt], 0, 0, 0);
      }
    }
    if constexpr (FIX) {
      bf16x8 a0 = zero8(), a1 = zero8();
      if (quad < 2) {
        a0 = *(const bf16x8*)(wext + (pr * 32 + l16) * 16 + quad * 8);
        a1 = *(const bf16x8*)(wext + (pr * 32 + 16 + l16) * 16 + quad * 8);
      }
#pragma unroll
      for (int nt = 0; nt < NT; ++nt) {
        acc0[nt] = __builtin_amdgcn_mfma_f32_16x16x32_bf16(a0, pf[nt], acc0[nt], 0, 0, 0);
        acc1[nt] = __builtin_amdgcn_mfma_f32_16x16x32_bf16(a1, pf[nt], acc1[nt], 0, 0, 0);
      }
    }
#pragma unroll
    for (int nt = 0; nt < NT; ++nt) hout[pr][nt] = pack_relu(acc0[nt], acc1[nt]);
  }
}

__global__ __launch_bounds__(512, 4) void nerf_kernel(
    const float* __restrict__ x,
    const float* __restrict__ b0, const float* __restrict__ b1,
    const float* __restrict__ b2, const float* __restrict__ b3,
    const float* __restrict__ bd, const float* __restrict__ bfv,
    const float* __restrict__ br, const float* __restrict__ bo,
    const __bf16* __restrict__ ws,
    float* __restrict__ out) {
  __shared__ __align__(16) __bf16 posb[512 * 16];   // 16 KiB
  __shared__ __align__(16) __bf16 sA[128 * 128];    // 32 KiB
  __shared__ __align__(16) __bf16 sB[128 * 128];    // 32 KiB  (total 80K -> 2 blk/CU)

  const int tid  = threadIdx.x;
  const int wv   = tid >> 6;
  const int lane = tid & 63;
  const int quad = lane >> 4;
  const int l16  = lane & 15;
  const int p0   = blockIdx.x * 512;
  const int pw   = wv * 64;

  // ---- stage posb (one point/thread) + issue W1->A, W2->B prefetch
  {
    const float* xp = x + (size_t)(p0 + tid) * 6;
    f32x2 a = *(const f32x2*)xp;
    f32x2 b = *(const f32x2*)(xp + 2);
    f32x2 c = *(const f32x2*)(xp + 4);
    float px = a[0], py = a[1], pz = b[0], vx = b[1], vy = c[0], vz = c[1];
    __bf16 phx = (__bf16)px, phy = (__bf16)py, phz = (__bf16)pz;
    __bf16 vhx = (__bf16)vx, vhy = (__bf16)vy, vhz = (__bf16)vz;
    __bf16 plx = (__bf16)(px - (float)phx), ply = (__bf16)(py - (float)phy), plz = (__bf16)(pz - (float)phz);
    __bf16 vlx = (__bf16)(vx - (float)vhx), vly = (__bf16)(vy - (float)vhy), vlz = (__bf16)(vz - (float)vhz);
    bf16x8 r0, r1;
    r0[0] = phx; r0[1] = phy; r0[2] = phz; r0[3] = plx; r0[4] = ply; r0[5] = plz; r0[6] = phx; r0[7] = phy;
    r1[0] = phz; r1[1] = vhx; r1[2] = vhy; r1[3] = vhz; r1[4] = vlx; r1[5] = vly; r1[6] = vlz; r1[7] = (__bf16)0.f;
    *(bf16x8*)(posb + tid * 16) = r0;
    *(bf16x8*)(posb + tid * 16 + 8) = r1;
  }
  stage_tile<32768>(ws + W1P, sA, wv, lane);
  stage_tile<32768>(ws + W2P, sB, wv, lane);

  // ---- preload l0 fixup weights (independent of posb)
  bf16x8 w0a[4], w0b[4];
#pragma unroll
  for (int pr = 0; pr < 4; ++pr) {
    w0a[pr] = zero8(); w0b[pr] = zero8();
    if (quad < 2) {
      w0a[pr] = *(const bf16x8*)(ws + W0E + (pr * 32 + l16) * 16 + quad * 8);
      w0b[pr] = *(const bf16x8*)(ws + W0E + (pr * 32 + 16 + l16) * 16 + quad * 8);
    }
  }
  __syncthreads();                                   // posb visible (drains vmem too)

  // ---- per-wave pos/vdir B-frags
  bf16x8 pf[NT];
#pragma unroll
  for (int nt = 0; nt < NT; ++nt) {
    pf[nt] = zero8();
    if (quad < 2) pf[nt] = *(const bf16x8*)(posb + (pw + nt * 16 + l16) * 16 + quad * 8);
  }

  bf16x8 hA[4][NT], hB[4][NT];

  // ---- layer 0: h0 = relu(pos @ w0 + b0), K=32 fixup MFMA
#pragma unroll
  for (int pr = 0; pr < 4; ++pr) {
    f32x4 acc0[NT], acc1[NT];
    f32x4 bv0 = *(const f32x4*)(b0 + pr * 32 + quad * 4);
    f32x4 bv1 = *(const f32x4*)(b0 + pr * 32 + 16 + quad * 4);
#pragma unroll
    for (int nt = 0; nt < NT; ++nt) { acc0[nt] = bv0; acc1[nt] = bv1; }
#pragma unroll
    for (int nt = 0; nt < NT; ++nt) {
      acc0[nt] = __builtin_amdgcn_mfma_f32_16x16x32_bf16(w0a[pr], pf[nt], acc0[nt], 0, 0, 0);
      acc1[nt] = __builtin_amdgcn_mfma_f32_16x16x32_bf16(w0b[pr], pf[nt], acc1[nt], 0, 0, 0);
    }
#pragma unroll
    for (int nt = 0; nt < NT; ++nt) hA[pr][nt] = pack_relu(acc0[nt], acc1[nt]);
  }
  __syncthreads();                                   // W1(A), W2(B) staged

  // ---- layer 1 from A
  mlayer<4, false>(sA, b1, nullptr, pf, hA, hB, l16, quad);
  __syncthreads();                                   // A free
  stage_tile<32768>(ws + W3P, sA, wv, lane);

  // ---- layer 2 from B (+pos fixup)
  mlayer<4, true>(sB, b2, ws + W2E, pf, hB, hA, l16, quad);
  __syncthreads();                                   // W3(A) staged, B free
  stage_tile<32768>(ws + WFP, sB, wv, lane);

  // ---- layer 3 from A
  mlayer<4, false>(sA, b3, nullptr, pf, hA, hB, l16, quad);
  __syncthreads();                                   // WF(B) staged, A free
  stage_tile<16384>(ws + WRP, sA, wv, lane);

  // ---- density = relu(h3 @ wd + bd) from global WDE
  {
    f32x4 accd[NT];
#pragma unroll
    for (int nt = 0; nt < NT; ++nt) accd[nt] = f32x4{0.f, 0.f, 0.f, 0.f};
    int drow = (l16 < 2) ? l16 : 0;
#pragma unroll
    for (int c = 0; c < 4; ++c) {
      bf16x8 ad = *(const bf16x8*)(ws + WDE + drow * 128 + c * 32 + quad * 8);
#pragma unroll
      for (int nt = 0; nt < NT; ++nt)
        accd[nt] = __builtin_amdgcn_mfma_f32_16x16x32_bf16(ad, hB[c][nt], accd[nt], 0, 0, 0);
    }
    float bdv = bd[0];
    if (quad == 0) {
#pragma unroll
      for (int nt = 0; nt < NT; ++nt)
        out[(size_t)3 * N_PTS + p0 + pw + nt * 16 + l16] =
            fmaxf(accd[nt][0] + accd[nt][1] + bdv, 0.f);
    }
  }

  // ---- features from B
  mlayer<4, false>(sB, bfv, nullptr, pf, hB, hA, l16, quad);
  __syncthreads();                                   // WR(A) staged

  // ---- r = relu([feat, vdir] @ wr + br) from A, 64 outputs
  bf16x8 hR[2][NT];
  mlayer<2, true>(sA, br, ws + WRE, pf, hA, hR, l16, quad);

  // ---- rgb = sigmoid(r @ wo + bo) from global WOE
  {
    f32x4 acco[NT];
#pragma unroll
    for (int nt = 0; nt < NT; ++nt) acco[nt] = f32x4{0.f, 0.f, 0.f, 0.f};
    int orow = l16 & 7;
#pragma unroll
    for (int c = 0; c < 2; ++c) {
      bf16x8 ao = *(const bf16x8*)(ws + WOE + orow * 64 + c * 32 + quad * 8);
#pragma unroll
      for (int nt = 0; nt < NT; ++nt)
        acco[nt] = __builtin_amdgcn_mfma_f32_16x16x32_bf16(ao, hR[c][nt], acco[nt], 0, 0, 0);
    }
    float bo0 = bo[0], bo1 = bo[1], bo2 = bo[2];
#pragma unroll
    for (int nt = 0; nt < NT; ++nt) {
      float lo0 = __shfl_xor(acco[nt][0], 16, 64);
      float lo1 = __shfl_xor(acco[nt][1], 16, 64);
      float lo2 = __shfl_xor(acco[nt][2], 16, 64);
      if (quad == 0) {
        size_t o = (size_t)(p0 + pw + nt * 16 + l16) * 3;
        float s0 = acco[nt][0] + lo0 + bo0;
        float s1 = acco[nt][1] + lo1 + bo1;
        float s2 = acco[nt][2] + lo2 + bo2;
        out[o + 0] = 1.f / (1.f + __expf(-s0));
        out[o + 1] = 1.f / (1.f + __expf(-s1));
        out[o + 2] = 1.f / (1.f + __expf(-s2));
      }
    }
  }
}

extern "C" void kernel_launch(void* const* d_in, const int* in_sizes, int n_in,
                              void* d_out, int out_size, void* d_ws, size_t ws_size,
                              hipStream_t stream) {
  const float* x  = (const float*)d_in[0];
  const float* w0 = (const float*)d_in[1];
  const float* b0 = (const float*)d_in[2];
  const float* w1 = (const float*)d_in[3];
  const float* b1 = (const float*)d_in[4];
  const float* w2 = (const float*)d_in[5];
  const float* b2 = (const float*)d_in[6];
  const float* w3 = (const float*)d_in[7];
  const float* b3 = (const float*)d_in[8];
  const float* wd = (const float*)d_in[9];
  const float* bd = (const float*)d_in[10];
  const float* wf = (const float*)d_in[11];
  const float* bfv= (const float*)d_in[12];
  const float* wr = (const float*)d_in[13];
  const float* br = (const float*)d_in[14];
  const float* wo = (const float*)d_in[15];
  const float* bo = (const float*)d_in[16];
  __bf16* ws = (__bf16*)d_ws;
  float* out = (float*)d_out;

  prep_kernel<<<311, 256, 0, stream>>>(w0, w1, w2, w3, wf, wr, wd, wo, ws);
  nerf_kernel<<<N_PTS / 512, 512, 0, stream>>>(x, b0, b1, b2, b3, bd, bfv, br, bo, ws, out);
}

// Round 3
// 202.836 us; speedup vs baseline: 2.1080x; 2.1080x over previous
//
#include <hip/hip_runtime.h>
#include <hip/hip_bf16.h>

#define N_PTS (4096 * 192)
#define NT 4            // point-tiles (of 16) per wave -> 64 points/wave

typedef __bf16 bf16x8 __attribute__((ext_vector_type(8)));
typedef float  f32x4  __attribute__((ext_vector_type(4)));
typedef float  f32x2  __attribute__((ext_vector_type(2)));

// ws layout (bf16 element offsets). Main tiles are [m][k'] with k rows permuted
// by kinv (so MFMA C-layout of layer l == B-frag layout of layer l+1) AND
// column-chunk XOR-swizzled (chunk' = chunk ^ (m&15)) so that a LINEAR
// global_load_lds copy produces a bank-conflict-free LDS image for
// ds_read_b128 at 256B row stride (read applies the same XOR == l16).
#define W1P 0          // 128x128
#define W2P 16384      // 128x128 (rows 0..127 of w2)
#define W3P 32768      // 128x128
#define WFP 49152      // 128x128
#define WRP 65536      // 64x128
#define W0E 73728      // 128x16  fixup vs posb (global-read, unswizzled)
#define W2E 75776      // 128x16
#define WRE 77824      // 64x16
#define WDE 78848      // 2x128   row0 = wd_hi[kinv], row1 = wd_lo[kinv]
#define WOE 79104      // 8x64    rows0-2 = wo_hi ch, rows4-6 = wo_lo ch
// total span = 79616 bf16 = 159,232 B

__device__ __forceinline__ int kinv(int k) {
  int c = k >> 5, q = (k >> 3) & 3, h = (k >> 2) & 1, r = k & 3;
  return (2 * c + h) * 16 + q * 4 + r;
}

__global__ void prep_kernel(const float* __restrict__ w0, const float* __restrict__ w1,
                            const float* __restrict__ w2, const float* __restrict__ w3,
                            const float* __restrict__ wf, const float* __restrict__ wr,
                            const float* __restrict__ wd, const float* __restrict__ wo,
                            __bf16* __restrict__ ws) {
  int i = blockIdx.x * 256 + threadIdx.x;
  if (i < 65536) {                       // w1,w2,w3,wf main tiles: k-permuted + swizzled
    int t = i >> 14, j = i & 16383, m = j >> 7, col = j & 127;
    int k = (((col >> 3) ^ (m & 15)) << 3) | (col & 7);
    int p = kinv(k);
    const float* w = (t == 0) ? w1 : (t == 1) ? w2 : (t == 2) ? w3 : wf;
    ws[i] = (__bf16)w[p * 128 + m];
  } else if (i < 73728) {                // wr main tile
    int j = i - 65536, m = j >> 7, col = j & 127;
    int k = (((col >> 3) ^ (m & 15)) << 3) | (col & 7);
    int p = kinv(k);
    ws[i] = (__bf16)wr[p * 64 + m];
  } else if (i < 75776) {                // W0E (k-space = posb, no permutation)
    int j = i - 73728, f = j >> 4, k = j & 15; float v = 0.f;
    if (k < 3)      v = w0[k * 128 + f];
    else if (k < 6) v = w0[(k - 3) * 128 + f];
    else if (k < 9) { float w = w0[(k - 6) * 128 + f]; v = w - (float)(__bf16)w; }
    ws[i] = (__bf16)v;
  } else if (i < 77824) {                // W2E
    int j = i - 75776, f = j >> 4, k = j & 15; float v = 0.f;
    if (k < 3)      v = w2[(128 + k) * 128 + f];
    else if (k < 6) v = w2[(128 + k - 3) * 128 + f];
    else if (k < 9) { float w = w2[(128 + k - 6) * 128 + f]; v = w - (float)(__bf16)w; }
    ws[i] = (__bf16)v;
  } else if (i < 78848) {                // WRE
    int j = i - 77824, n = j >> 4, k = j & 15; float v = 0.f;
    if (k >= 9 && k < 15) v = wr[(128 + ((k - 9) % 3)) * 64 + n];
    ws[i] = (__bf16)v;
  } else if (i < 79104) {                // WDE: wd hi/lo, k-permuted
    int j = i - 78848, row = j >> 7, k = j & 127, p = kinv(k);
    float v = wd[p];
    ws[i] = (row == 0) ? (__bf16)v : (__bf16)(v - (float)(__bf16)v);
  } else if (i < 79616) {                // WOE: wo hi/lo, k64-permuted
    int j = i - 79104, row = j >> 6, k = j & 63, p = kinv(k);
    float v = 0.f;
    if (row < 3)                 v = wo[p * 3 + row];
    else if (row >= 4 && row < 7) { float w = wo[p * 3 + row - 4]; v = w - (float)(__bf16)w; }
    ws[i] = (__bf16)v;
  }
}

__device__ __forceinline__ bf16x8 zero8() {
  bf16x8 z;
#pragma unroll
  for (int i = 0; i < 8; ++i) z[i] = (__bf16)0.f;
  return z;
}

__device__ __forceinline__ bf16x8 pack_relu(f32x4 e, f32x4 o) {
  bf16x8 v;
#pragma unroll
  for (int r = 0; r < 4; ++r) {
    v[r]     = (__bf16)fmaxf(e[r], 0.f);
    v[4 + r] = (__bf16)fmaxf(o[r], 0.f);
  }
  return v;
}

// Cooperative global->LDS stage of NB bytes (256 threads, 16B/lane/round).
template <int NB>
__device__ __forceinline__ void stage_tile(const __bf16* __restrict__ gsrc,
                                           __bf16* lds, int wv, int lane) {
  const char* g = (const char*)gsrc;
  char* l = (char*)lds;
#pragma unroll
  for (int r = 0; r < NB; r += 4096) {
    const char* src = g + r + wv * 1024 + lane * 16;
    char* dst = l + r + wv * 1024;                        // wave-uniform base
    __builtin_amdgcn_global_load_lds(
        (const __attribute__((address_space(1))) void*)src,
        (__attribute__((address_space(3))) void*)dst, 16, 0, 0);
  }
}

// One layer from LDS-resident swizzled weights. K=128, acts in registers.
template <int NPAIR, bool FIX>
__device__ __forceinline__ void mlayer(const __bf16* __restrict__ wlds,
                                       const float* __restrict__ bias,
                                       const __bf16* __restrict__ wext,
                                       const bf16x8 (&pf)[NT],
                                       const bf16x8 (&hin)[4][NT],
                                       bf16x8 (&hout)[NPAIR][NT],
                                       int l16, int quad) {
#pragma unroll
  for (int pr = 0; pr < NPAIR; ++pr) {
    f32x4 acc0[NT], acc1[NT];
    f32x4 bv0 = *(const f32x4*)(bias + pr * 32 + quad * 4);
    f32x4 bv1 = *(const f32x4*)(bias + pr * 32 + 16 + quad * 4);
#pragma unroll
    for (int nt = 0; nt < NT; ++nt) { acc0[nt] = bv0; acc1[nt] = bv1; }
#pragma unroll
    for (int c = 0; c < 4; ++c) {
      int chunk = ((c * 4 + quad) ^ l16) << 3;           // swizzled column chunk
      bf16x8 a0 = *(const bf16x8*)(wlds + (pr * 32 + l16) * 128 + chunk);
      bf16x8 a1 = *(const bf16x8*)(wlds + (pr * 32 + 16 + l16) * 128 + chunk);
#pragma unroll
      for (int nt = 0; nt < NT; ++nt) {
        acc0[nt] = __builtin_amdgcn_mfma_f32_16x16x32_bf16(a0, hin[c][nt], acc0[nt], 0, 0, 0);
        acc1[nt] = __builtin_amdgcn_mfma_f32_16x16x32_bf16(a1, hin[c][nt], acc1[nt], 0, 0, 0);
      }
    }
    if constexpr (FIX) {
      bf16x8 a0 = zero8(), a1 = zero8();
      if (quad < 2) {
        a0 = *(const bf16x8*)(wext + (pr * 32 + l16) * 16 + quad * 8);
        a1 = *(const bf16x8*)(wext + (pr * 32 + 16 + l16) * 16 + quad * 8);
      }
#pragma unroll
      for (int nt = 0; nt < NT; ++nt) {
        acc0[nt] = __builtin_amdgcn_mfma_f32_16x16x32_bf16(a0, pf[nt], acc0[nt], 0, 0, 0);
        acc1[nt] = __builtin_amdgcn_mfma_f32_16x16x32_bf16(a1, pf[nt], acc1[nt], 0, 0, 0);
      }
    }
#pragma unroll
    for (int nt = 0; nt < NT; ++nt) hout[pr][nt] = pack_relu(acc0[nt], acc1[nt]);
  }
}

__global__ __launch_bounds__(256, 2) void nerf_kernel(
    const float* __restrict__ x,
    const float* __restrict__ b0, const float* __restrict__ b1,
    const float* __restrict__ b2, const float* __restrict__ b3,
    const float* __restrict__ bd, const float* __restrict__ bfv,
    const float* __restrict__ br, const float* __restrict__ bo,
    const __bf16* __restrict__ ws,
    float* __restrict__ out) {
  __shared__ __align__(16) __bf16 posb[256 * 16];   //  8 KiB
  __shared__ __align__(16) __bf16 sA[128 * 128];    // 32 KiB
  __shared__ __align__(16) __bf16 sB[128 * 128];    // 32 KiB  (72K -> 2 blk/CU)

  const int tid  = threadIdx.x;
  const int wv   = tid >> 6;
  const int lane = tid & 63;
  const int quad = lane >> 4;
  const int l16  = lane & 15;
  const int p0   = blockIdx.x * 256;
  const int pw   = wv * 64;

  // ---- issue W1->A, W2->B prefetch first (latency hidden under posb+layer0)
  stage_tile<32768>(ws + W1P, sA, wv, lane);
  stage_tile<32768>(ws + W2P, sB, wv, lane);

  // ---- stage posb (one point/thread). Each wave's 64 threads write exactly
  //      its own 64 points, so reads below are wave-local: NO barrier needed.
  {
    const float* xp = x + (size_t)(p0 + tid) * 6;
    f32x2 a = *(const f32x2*)xp;
    f32x2 b = *(const f32x2*)(xp + 2);
    f32x2 c = *(const f32x2*)(xp + 4);
    float px = a[0], py = a[1], pz = b[0], vx = b[1], vy = c[0], vz = c[1];
    __bf16 phx = (__bf16)px, phy = (__bf16)py, phz = (__bf16)pz;
    __bf16 vhx = (__bf16)vx, vhy = (__bf16)vy, vhz = (__bf16)vz;
    __bf16 plx = (__bf16)(px - (float)phx), ply = (__bf16)(py - (float)phy), plz = (__bf16)(pz - (float)phz);
    __bf16 vlx = (__bf16)(vx - (float)vhx), vly = (__bf16)(vy - (float)vhy), vlz = (__bf16)(vz - (float)vhz);
    bf16x8 r0, r1;
    r0[0] = phx; r0[1] = phy; r0[2] = phz; r0[3] = plx; r0[4] = ply; r0[5] = plz; r0[6] = phx; r0[7] = phy;
    r1[0] = phz; r1[1] = vhx; r1[2] = vhy; r1[3] = vhz; r1[4] = vlx; r1[5] = vly; r1[6] = vlz; r1[7] = (__bf16)0.f;
    *(bf16x8*)(posb + tid * 16) = r0;
    *(bf16x8*)(posb + tid * 16 + 8) = r1;
  }

  // ---- preload l0 fixup weights (independent global loads)
  bf16x8 w0a[4], w0b[4];
#pragma unroll
  for (int pr = 0; pr < 4; ++pr) {
    w0a[pr] = zero8(); w0b[pr] = zero8();
    if (quad < 2) {
      w0a[pr] = *(const bf16x8*)(ws + W0E + (pr * 32 + l16) * 16 + quad * 8);
      w0b[pr] = *(const bf16x8*)(ws + W0E + (pr * 32 + 16 + l16) * 16 + quad * 8);
    }
  }

  // ---- per-wave pos/vdir B-frags (wave-local LDS read; lgkm wait auto)
  bf16x8 pf[NT];
#pragma unroll
  for (int nt = 0; nt < NT; ++nt) {
    pf[nt] = zero8();
    if (quad < 2) pf[nt] = *(const bf16x8*)(posb + (pw + nt * 16 + l16) * 16 + quad * 8);
  }

  bf16x8 hA[4][NT], hB[4][NT];

  // ---- layer 0: h0 = relu(pos @ w0 + b0), K=32 fixup MFMA (hides staging)
#pragma unroll
  for (int pr = 0; pr < 4; ++pr) {
    f32x4 acc0[NT], acc1[NT];
    f32x4 bv0 = *(const f32x4*)(b0 + pr * 32 + quad * 4);
    f32x4 bv1 = *(const f32x4*)(b0 + pr * 32 + 16 + quad * 4);
#pragma unroll
    for (int nt = 0; nt < NT; ++nt) { acc0[nt] = bv0; acc1[nt] = bv1; }
#pragma unroll
    for (int nt = 0; nt < NT; ++nt) {
      acc0[nt] = __builtin_amdgcn_mfma_f32_16x16x32_bf16(w0a[pr], pf[nt], acc0[nt], 0, 0, 0);
      acc1[nt] = __builtin_amdgcn_mfma_f32_16x16x32_bf16(w0b[pr], pf[nt], acc1[nt], 0, 0, 0);
    }
#pragma unroll
    for (int nt = 0; nt < NT; ++nt) hA[pr][nt] = pack_relu(acc0[nt], acc1[nt]);
  }
  __syncthreads();                                   // W1(A), W2(B) staged & visible

  // ---- layer 1 from A
  mlayer<4, false>(sA, b1, nullptr, pf, hA, hB, l16, quad);
  __syncthreads();                                   // all waves done with A
  stage_tile<32768>(ws + W3P, sA, wv, lane);

  // ---- layer 2 from B (+pos fixup); W3 staging lands underneath
  mlayer<4, true>(sB, b2, ws + W2E, pf, hB, hA, l16, quad);
  __syncthreads();                                   // W3(A) visible, B free
  stage_tile<32768>(ws + WFP, sB, wv, lane);

  // ---- layer 3 from A; WF staging lands underneath
  mlayer<4, false>(sA, b3, nullptr, pf, hA, hB, l16, quad);
  __syncthreads();                                   // WF(B) visible, A free
  stage_tile<16384>(ws + WRP, sA, wv, lane);

  // ---- density = relu(h3 @ wd + bd) from global WDE
  {
    f32x4 accd[NT];
#pragma unroll
    for (int nt = 0; nt < NT; ++nt) accd[nt] = f32x4{0.f, 0.f, 0.f, 0.f};
    int drow = (l16 < 2) ? l16 : 0;
#pragma unroll
    for (int c = 0; c < 4; ++c) {
      bf16x8 ad = *(const bf16x8*)(ws + WDE + drow * 128 + c * 32 + quad * 8);
#pragma unroll
      for (int nt = 0; nt < NT; ++nt)
        accd[nt] = __builtin_amdgcn_mfma_f32_16x16x32_bf16(ad, hB[c][nt], accd[nt], 0, 0, 0);
    }
    float bdv = bd[0];
    if (quad == 0) {
#pragma unroll
      for (int nt = 0; nt < NT; ++nt)
        out[(size_t)3 * N_PTS + p0 + pw + nt * 16 + l16] =
            fmaxf(accd[nt][0] + accd[nt][1] + bdv, 0.f);
    }
  }

  // ---- features = relu(h3 @ wf + bf) from B; WR staging lands underneath
  mlayer<4, false>(sB, bfv, nullptr, pf, hB, hA, l16, quad);
  __syncthreads();                                   // WR(A) visible

  // ---- r = relu([feat, vdir] @ wr + br) from A, 64 outputs
  bf16x8 hR[2][NT];
  mlayer<2, true>(sA, br, ws + WRE, pf, hA, hR, l16, quad);

  // ---- rgb = sigmoid(r @ wo + bo) from global WOE
  {
    f32x4 acco[NT];
#pragma unroll
    for (int nt = 0; nt < NT; ++nt) acco[nt] = f32x4{0.f, 0.f, 0.f, 0.f};
    int orow = l16 & 7;
#pragma unroll
    for (int c = 0; c < 2; ++c) {
      bf16x8 ao = *(const bf16x8*)(ws + WOE + orow * 64 + c * 32 + quad * 8);
#pragma unroll
      for (int nt = 0; nt < NT; ++nt)
        acco[nt] = __builtin_amdgcn_mfma_f32_16x16x32_bf16(ao, hR[c][nt], acco[nt], 0, 0, 0);
    }
    float bo0 = bo[0], bo1 = bo[1], bo2 = bo[2];
#pragma unroll
    for (int nt = 0; nt < NT; ++nt) {
      float lo0 = __shfl_xor(acco[nt][0], 16, 64);
      float lo1 = __shfl_xor(acco[nt][1], 16, 64);
      float lo2 = __shfl_xor(acco[nt][2], 16, 64);
      if (quad == 0) {
        size_t o = (size_t)(p0 + pw + nt * 16 + l16) * 3;
        float s0 = acco[nt][0] + lo0 + bo0;
        float s1 = acco[nt][1] + lo1 + bo1;
        float s2 = acco[nt][2] + lo2 + bo2;
        out[o + 0] = 1.f / (1.f + __expf(-s0));
        out[o + 1] = 1.f / (1.f + __expf(-s1));
        out[o + 2] = 1.f / (1.f + __expf(-s2));
      }
    }
  }
}

extern "C" void kernel_launch(void* const* d_in, const int* in_sizes, int n_in,
                              void* d_out, int out_size, void* d_ws, size_t ws_size,
                              hipStream_t stream) {
  const float* x  = (const float*)d_in[0];
  const float* w0 = (const float*)d_in[1];
  const float* b0 = (const float*)d_in[2];
  const float* w1 = (const float*)d_in[3];
  const float* b1 = (const float*)d_in[4];
  const float* w2 = (const float*)d_in[5];
  const float* b2 = (const float*)d_in[6];
  const float* w3 = (const float*)d_in[7];
  const float* b3 = (const float*)d_in[8];
  const float* wd = (const float*)d_in[9];
  const float* bd = (const float*)d_in[10];
  const float* wf = (const float*)d_in[11];
  const float* bfv= (const float*)d_in[12];
  const float* wr = (const float*)d_in[13];
  const float* br = (const float*)d_in[14];
  const float* wo = (const float*)d_in[15];
  const float* bo = (const float*)d_in[16];
  __bf16* ws = (__bf16*)d_ws;
  float* out = (float*)d_out;

  prep_kernel<<<311, 256, 0, stream>>>(w0, w1, w2, w3, wf, wr, wd, wo, ws);
  nerf_kernel<<<N_PTS / 256, 256, 0, stream>>>(x, b0, b1, b2, b3, bd, bfv, br, bo, ws, out);
}